// Round 8
// baseline (169.696 us; speedup 1.0000x reference)
//
#include <hip/hip_runtime.h>
#include <math.h>

#define R_NODES 1152
#define DIGITS 10
#define OUT_CH 16
#define IN_CH 8
#define BATCH 256
#define COLS 160            // DIGITS*OUT_CH
#define W_PER_R 1280        // DIGITS*OUT_CH*IN_CH
#define NSPLIT 144          // K-split: 8 r-rows per block
#define YB_S 4              // k_s batch blocks (64 b each)
#define YBLK 8              // k_a batch blocks (32 b each)
#define SGRP 102            // W-LDS colgroup stride: g*6 mod 32 distinct for g=0..15
#define SROW (16 * SGRP)    // 1632 floats per r-row
#define UPAD 68             // u-LDS batch stride: lane stride 68%32=4 -> conflict-free
#define AB_STRIDE (YBLK * R_NODES * DIGITS)   // 92160 floats per ab iteration-buffer

// ---------- s partials + fused per-block softmax ----------
// grid (144, 4): blockIdx.x = 8-row slice, blockIdx.y = 64-batch block.
// 256 threads = 16 colgroups (g) x 16 bs; each thread does batches
// b0 + bs + jj*16 (jj=0..3).
// BOTH operands staged in LDS: W (52.2 KB, swizzled) and u (17.4 KB, pad 68).
// r7 lesson: u straight from global was a 16-address gather per load instr
// (36 KB batch stride) -> latency-bound. Now: coalesced stage, LDS-only loop.
// u-loads issued BEFORE W-loads so ut-writes don't drain W from vmcnt.
__global__ __launch_bounds__(256) void k_s(
    const float* __restrict__ u,      // [B][R][8]
    const float* __restrict__ W,      // [R][10][16][8]
    const float* __restrict__ ab,     // [nbuf][YBLK][R][10] agreement partials
    float* __restrict__ part,         // [NSPLIT][B][160]
    float* __restrict__ sq,
    int nbuf)
{
    __shared__ float wt[8 * SROW];      // 52,224 B
    __shared__ float ut[64 * UPAD];     // 17,408 B
    __shared__ float cs[80];            // c for this block's 8 rows

    const int split = blockIdx.x;
    const int b0 = blockIdx.y * 64;
    const int t = threadIdx.x;
    const int g = t & 15;
    const int bs = t >> 4;
    const int r0 = split * 8;

    if (split == 0 && blockIdx.y == 0 && t == 0) *sq = 0.f;

    // ---- 1. issue u-tile loads FIRST (4 float4/thread, fully coalesced)
    float4 ur[4];
    int ub_[4], uq_[4];
#pragma unroll
    for (int p = 0; p < 4; ++p) {
        int idx = t + p * 256;            // 0..1023
        int b = idx >> 4, q = idx & 15;   // batch 0..63, float4 0..15
        ub_[p] = b; uq_[p] = q;
        ur[p] = ((const float4*)(u + (size_t)(b0 + b) * (R_NODES * IN_CH)
                                   + (size_t)r0 * IN_CH))[q];
    }
    // ---- 2. issue W loads (10 float4/thread)
    float4 wr[10];
    {
        const float4* Wg = (const float4*)(W + (size_t)r0 * W_PER_R);
#pragma unroll
        for (int p = 0; p < 10; ++p) wr[p] = Wg[t + p * 256];
    }
    // ---- 3. write u-tile (waits only on u loads; W stays in flight)
#pragma unroll
    for (int p = 0; p < 4; ++p)
        *(float4*)&ut[ub_[p] * UPAD + uq_[p] * 4] = ur[p];

    // ---- 4. c logits for rows r0..r0+7 (0 if nbuf==0 -> softmax = 0.1)
    if (t < 80) {
        float a = 0.f;
        int r_l = t / 10, d = t - r_l * 10;
        const float* p0 = ab + (size_t)(r0 + r_l) * DIGITS + d;
        for (int bu = 0; bu < nbuf; ++bu)
#pragma unroll
            for (int yy = 0; yy < YBLK; ++yy)
                a += p0[(size_t)bu * AB_STRIDE + (size_t)yy * (R_NODES * DIGITS)];
        cs[t] = a;
    }
    __syncthreads();
    if (t < 8) {
        float e[DIGITS];
        float m = -1e30f;
#pragma unroll
        for (int d = 0; d < DIGITS; ++d) m = fmaxf(m, cs[t*10 + d]);
        float ssum = 0.f;
#pragma unroll
        for (int d = 0; d < DIGITS; ++d) { e[d] = expf(cs[t*10 + d] - m); ssum += e[d]; }
        float inv = 1.f / ssum;
#pragma unroll
        for (int d = 0; d < DIGITS; ++d) cs[t*10 + d] = e[d] * inv;
    }
    __syncthreads();

    // ---- 5. scale W by c and write to swizzled LDS
#pragma unroll
    for (int p = 0; p < 10; ++p) {
        int e4 = t + p * 256;             // float4 index 0..2559 over 8 rows
        int e  = e4 * 4;
        int r_l = e4 / 320;               // 320 float4 per row
        int rem = e - r_l * W_PER_R;
        int col = rem >> 3, i0 = e & 7;   // i0 in {0,4}
        int cg = col / 10, cj = col - cg * 10;
        float cv = cs[r_l * 10 + (col >> 4)];
        float2* dst = (float2*)&wt[r_l * SROW + cg * SGRP + cj * 10 + i0];
        dst[0] = make_float2(wr[p].x * cv, wr[p].y * cv);
        dst[1] = make_float2(wr[p].z * cv, wr[p].w * cv);
    }
    __syncthreads();

    // ---- 6. compute: pure LDS + FMA
    float acc[4][10];
#pragma unroll
    for (int jj = 0; jj < 4; ++jj)
#pragma unroll
        for (int j = 0; j < 10; ++j) acc[jj][j] = 0.f;

#pragma unroll 2
    for (int r_l = 0; r_l < 8; ++r_l) {
        float uu[4][8];
#pragma unroll
        for (int jj = 0; jj < 4; ++jj) {
            const float* up = &ut[(bs + jj * 16) * UPAD + r_l * 8];
            float4 a0 = *(const float4*)up;
            float4 a1 = *(const float4*)(up + 4);
            uu[jj][0]=a0.x; uu[jj][1]=a0.y; uu[jj][2]=a0.z; uu[jj][3]=a0.w;
            uu[jj][4]=a1.x; uu[jj][5]=a1.y; uu[jj][6]=a1.z; uu[jj][7]=a1.w;
        }
        const float* wrow = &wt[r_l * SROW + g * SGRP];
#pragma unroll
        for (int j = 0; j < 10; ++j) {
            const float2* wp = (const float2*)(wrow + j * 10);
            float2 w01 = wp[0], w23 = wp[1], w45 = wp[2], w67 = wp[3];
#pragma unroll
            for (int jj = 0; jj < 4; ++jj) {
                float a = acc[jj][j];
                a = fmaf(w01.x, uu[jj][0], a);
                a = fmaf(w01.y, uu[jj][1], a);
                a = fmaf(w23.x, uu[jj][2], a);
                a = fmaf(w23.y, uu[jj][3], a);
                a = fmaf(w45.x, uu[jj][4], a);
                a = fmaf(w45.y, uu[jj][5], a);
                a = fmaf(w67.x, uu[jj][6], a);
                a = fmaf(w67.y, uu[jj][7], a);
                acc[jj][j] = a;
            }
        }
    }

    // deterministic partial write (no atomics)
    float* pp = part + (size_t)split * (BATCH * COLS) + (size_t)b0 * COLS;
#pragma unroll
    for (int jj = 0; jj < 4; ++jj) {
        float* row = pp + (size_t)(bs + jj * 16) * COLS + g * 10;
#pragma unroll
        for (int j = 0; j < 10; ++j) row[j] = acc[jj][j];
    }
}

// ---------- reduce partials -> s ; accumulate global sum of squares ----------
__global__ void k_sq(const float* __restrict__ part,
                     float* __restrict__ s,
                     float* __restrict__ sq)
{
    const int t = threadIdx.x;
    const int e0 = blockIdx.x * 64;
    const int el = t & 63, q = t >> 6;
    float v = 0.f;
    for (int sp = q; sp < NSPLIT; sp += 4)
        v += part[(size_t)sp * (BATCH * COLS) + e0 + el];
    __shared__ float red[256];
    red[t] = v;
    __syncthreads();
    if (t < 64) {
        float vv = red[t] + red[t + 64] + red[t + 128] + red[t + 192];
        s[e0 + t] = vv;
        float x = vv * vv;
#pragma unroll
        for (int off = 32; off > 0; off >>= 1)
            x += __shfl_down(x, off, 64);
        if (t == 0) atomicAdd(sq, x);
    }
}

// ---------- agreement partials: ab[y][r,d] = scale * sum_{b in y,o} u_hat*s ----------
__global__ __launch_bounds__(256) void k_a(
    const float* __restrict__ u,
    const float* __restrict__ W,
    const float* __restrict__ s,
    const float* __restrict__ sq,
    float* __restrict__ ab)
{
    __shared__ float st[32 * COLS];   // 20.5 KB
    __shared__ float ut[32 * 64];     // 8 KB
    const int t = threadIdx.x;
    const int rblk = blockIdx.x;
    const int r = rblk * 8 + (t >> 5);
    const int tt = t & 31;
    const int bstart = blockIdx.y * 32;

    {
        const float4* sp = (const float4*)(s + (size_t)bstart * COLS);
#pragma unroll
        for (int p = 0; p < 5; ++p) ((float4*)st)[t + p * 256] = sp[t + p * 256];
    }
#pragma unroll
    for (int p = 0; p < 2; ++p) {
        int idx = t + p * 256;
        int bb = idx >> 4, qq = idx & 15;
        ((float4*)ut)[idx] =
            ((const float4*)(u + (size_t)(bstart + bb) * (R_NODES*IN_CH) + (size_t)rblk * 64))[qq];
    }

    float wreg[5][8];
#pragma unroll
    for (int k = 0; k < 5; ++k) {
        const float4* wp = (const float4*)(W + (size_t)r * W_PER_R + (size_t)(tt + 32*k) * IN_CH);
        float4 w0 = wp[0], w1 = wp[1];
        wreg[k][0]=w0.x; wreg[k][1]=w0.y; wreg[k][2]=w0.z; wreg[k][3]=w0.w;
        wreg[k][4]=w1.x; wreg[k][5]=w1.y; wreg[k][6]=w1.z; wreg[k][7]=w1.w;
    }
    __syncthreads();

    float acc[5] = {0.f, 0.f, 0.f, 0.f, 0.f};
#pragma unroll 2
    for (int b = 0; b < 32; ++b) {
        const float* ub = &ut[b * 64 + (t >> 5) * 8];
        float4 a0 = *(const float4*)ub;
        float4 a1 = *(const float4*)(ub + 4);
        const float* sb = &st[b * COLS];
#pragma unroll
        for (int k = 0; k < 5; ++k) {
            float vv = sb[tt + 32*k];
            float uh;
            uh = wreg[k][0] * a0.x;
            uh = fmaf(wreg[k][1], a0.y, uh);
            uh = fmaf(wreg[k][2], a0.z, uh);
            uh = fmaf(wreg[k][3], a0.w, uh);
            uh = fmaf(wreg[k][4], a1.x, uh);
            uh = fmaf(wreg[k][5], a1.y, uh);
            uh = fmaf(wreg[k][6], a1.z, uh);
            uh = fmaf(wreg[k][7], a1.w, uh);
            acc[k] = fmaf(uh, vv, acc[k]);
        }
    }
    float q = *sq;
    float scale = sqrtf(q) / (1.f + q);
    float* abp = ab + (size_t)blockIdx.y * (R_NODES * DIGITS) + r * DIGITS;
#pragma unroll
    for (int k = 0; k < 5; ++k) {
        float x = acc[k] * scale;
        x += __shfl_xor(x, 1, 64);
        x += __shfl_xor(x, 2, 64);
        x += __shfl_xor(x, 4, 64);
        x += __shfl_xor(x, 8, 64);
        if ((tt & 15) == 0) {
            int d = (tt >> 4) + 2*k;
            abp[d] = x;
        }
    }
}

// ---------- final output: v = s * sqrt(sq)/(1+sq) ----------
__global__ void k_scale(const float* __restrict__ s,
                        const float* __restrict__ sq,
                        float* __restrict__ out)
{
    int e = blockIdx.x * 256 + threadIdx.x;
    float q = *sq;
    float scale = sqrtf(q) / (1.f + q);
    out[e] = s[e] * scale;
}

extern "C" void kernel_launch(void* const* d_in, const int* in_sizes, int n_in,
                              void* d_out, int out_size, void* d_ws, size_t ws_size,
                              hipStream_t stream)
{
    const float* u = (const float*)d_in[0];   // (256, 1152, 8)
    const float* W = (const float*)d_in[1];   // (1, 1152, 10, 16, 8)
    float* out = (float*)d_out;               // (256, 10, 16)
    float* ws = (float*)d_ws;

    float* s    = ws;                          // 40960 floats
    float* sq   = ws + 40960;                  // 1 (padded to 64)
    float* ab   = ws + 41024;                  // 2 * 92160
    float* part = ws + 41024 + 2 * AB_STRIDE;  // 144 * 40960 (~23.6 MB; ws is 256 MiB)

    for (int it = 0; it < 3; ++it) {
        k_s<<<dim3(NSPLIT, YB_S), dim3(256), 0, stream>>>(u, W, ab, part, sq, it);
        k_sq<<<dim3(BATCH * COLS / 64), dim3(256), 0, stream>>>(part, s, sq);
        if (it < 2)
            k_a<<<dim3(R_NODES / 8, YBLK), dim3(256), 0, stream>>>(u, W, s, sq,
                                                                   ab + (size_t)it * AB_STRIDE);
        else
            k_scale<<<dim3(BATCH * COLS / 256), dim3(256), 0, stream>>>(s, sq, out);
    }
}